// Round 1
// baseline (76.228 us; speedup 1.0000x reference)
//
#include <hip/hip_runtime.h>

// FinalLayer: out[b,m] = bias + sum_c w_c * sum_n y[b,n,c] * exp(-0.5*(x_n-t_m)^2 * exp(-2*sigma_c))
// Shapes: x(B,N_IN) y(B,N_IN,C) t(B,N_OUT) sigma(C) w(C) b(1); out flat B*N_OUT fp32.
//
// sigma is channel-uniform for these inputs -> exact factorization:
//   out[b,m] = bias + sum_n ytil[b,n] * exp2(-((x_n - t_m)*s)^2),
//   ytil[b,n] = sum_c w_c y[b,n,c],  s = sqrt(0.5*log2(e))*exp(-sigma0)
// Uniformity checked on-device (__ballot); correct per-channel fallback kept.
//
// This version: SINGLE dispatch (prep fused into main; each block rebuilds its
// batch's 512 ytil values in LDS via float4-dot + 4-step shuffle — ~700 cycles,
// cheaper than a second kernel launch). Grid widened 64 -> 256 blocks
// (MTILE 64 -> 16, 16-way n-split) so all 256 CUs are used. No workspace use.
constexpr int Bb   = 4;
constexpr int NIN  = 512;
constexpr int NOUT = 1024;
constexpr int CC   = 64;    // == wavefront size

constexpr int MTILE = 16;   // m per block; block = 256 threads = 4 waves

__global__ __launch_bounds__(256) void rbf_fused(
    const float* __restrict__ x,     const float* __restrict__ y,
    const float* __restrict__ t,     const float* __restrict__ sigma,
    const float* __restrict__ w,     const float* __restrict__ bias,
    float* __restrict__ out)
{
    __shared__ float xs[NIN];    // x[b,n] * s
    __shared__ float yt[NIN];    // sum_c w_c y[b,n,c]
    __shared__ float part[64];   // [g][msub] cross-wave partials

    const int tid  = threadIdx.x;
    const int lane = tid & 63;
    const int g    = tid >> 6;                    // wave id 0..3
    const int mt   = blockIdx.x & (NOUT / MTILE - 1);  // m-tile 0..63
    const int b    = blockIdx.x >> 6;             // batch

    const float s0  = sigma[0];
    const bool  uni = (__ballot(sigma[lane] == s0) == ~0ull);  // block-uniform

    if (uni) {
        const float s = 0.84932180f * __expf(-s0);  // sqrt(0.5*log2e)*exp(-sigma0)

        // ---- phase 1a: xs[n] = x[b,n]*s (coalesced, 2 per thread) ----
        xs[tid]       = x[b * NIN + tid]       * s;
        xs[tid + 256] = x[b * NIN + tid + 256] * s;

        // ---- phase 1b: yt[n] = sum_c w_c y[b,n,c] ----
        // per wave: 128 rows, 4 rows/iter; lane = (row r 0..3) x (float4 group cg 0..15)
        const int    r  = lane >> 4;
        const int    cg = lane & 15;
        const float4 wv = ((const float4*)w)[cg];
        const float4* __restrict__ y4 = (const float4*)(y + (size_t)b * NIN * CC);
#pragma unroll 4
        for (int it = 0; it < NIN / 16; ++it) {          // 32 iters
            const int n = g * (NIN / 4) + it * 4 + r;
            const float4 v = y4[n * (CC / 4) + cg];      // coalesced dwordx4
            float p = v.x * wv.x + v.y * wv.y + v.z * wv.z + v.w * wv.w;
            p += __shfl_xor(p, 1, 64);                   // reduce over cg (16 lanes)
            p += __shfl_xor(p, 2, 64);
            p += __shfl_xor(p, 4, 64);
            p += __shfl_xor(p, 8, 64);
            if (cg == 0) yt[n] = p;
        }
        __syncthreads();

        // ---- phase 2: 16 m per block, 16-way n split (4 lanes x 4 waves) ----
        const int msub = lane >> 2;             // 0..15
        const int nsub = g * 4 + (lane & 3);    // 0..15
        const int m    = mt * MTILE + msub;
        const float tm = t[b * NOUT + m] * s;
        // n = nsub + 16*k: 4 distinct LDS addresses/wave on distinct banks,
        // same-m lanes broadcast -> conflict-free
        float a0 = 0.f, a1 = 0.f, a2 = 0.f, a3 = 0.f;
#pragma unroll
        for (int k = 0; k < 32; k += 4) {       // 4 chains for exp-latency ILP
            const int n0 = nsub + 16 * k;
            const float d0 = xs[n0]      - tm;
            const float d1 = xs[n0 + 16] - tm;
            const float d2 = xs[n0 + 32] - tm;
            const float d3 = xs[n0 + 48] - tm;
            a0 += __builtin_amdgcn_exp2f(-(d0 * d0)) * yt[n0];
            a1 += __builtin_amdgcn_exp2f(-(d1 * d1)) * yt[n0 + 16];
            a2 += __builtin_amdgcn_exp2f(-(d2 * d2)) * yt[n0 + 32];
            a3 += __builtin_amdgcn_exp2f(-(d3 * d3)) * yt[n0 + 48];
        }
        float acc = (a0 + a1) + (a2 + a3);
        acc += __shfl_xor(acc, 1, 64);          // reduce over lane&3
        acc += __shfl_xor(acc, 2, 64);
        if ((lane & 3) == 0) part[g * 16 + msub] = acc;
        __syncthreads();
        if (tid < 16) {                          // cross-wave + bias + store
            const float rsum = (part[tid] + part[16 + tid]) +
                               (part[32 + tid] + part[48 + tid]) + bias[0];
            out[b * NOUT + mt * MTILE + tid] = rsum;
        }
    } else {
        // general per-channel path: lane = c; wave g handles 4 m values
        const float kc2 = -0.72134752f * __expf(-2.0f * sigma[lane]);
        const float wc  = w[lane];
        const float* __restrict__ xb = x + b * NIN;
        const float* __restrict__ yb = y + (size_t)b * NIN * CC + lane;
        for (int j = 0; j < 4; ++j) {
            const int   mm = mt * MTILE + g * 4 + j;
            const float tm = t[b * NOUT + mm];
            float acc = 0.f;
            for (int n = 0; n < NIN; ++n) {
                const float d = xb[n] - tm;
                acc += __builtin_amdgcn_exp2f(d * d * kc2) * yb[(size_t)n * CC];
            }
            float p = acc * wc;
#pragma unroll
            for (int off = 32; off > 0; off >>= 1) p += __shfl_xor(p, off, 64);
            if (lane == 0) out[b * NOUT + mm] = p + bias[0];
        }
    }
}

extern "C" void kernel_launch(void* const* d_in, const int* in_sizes, int n_in,
                              void* d_out, int out_size, void* d_ws, size_t ws_size,
                              hipStream_t stream) {
    const float* x     = (const float*)d_in[0];
    const float* y     = (const float*)d_in[1];
    const float* t     = (const float*)d_in[2];
    const float* sigma = (const float*)d_in[3];
    const float* w     = (const float*)d_in[4];
    const float* bias  = (const float*)d_in[5];
    float* out = (float*)d_out;
    (void)d_ws; (void)ws_size;

    rbf_fused<<<Bb * (NOUT / MTILE), 256, 0, stream>>>(x, y, t, sigma, w, bias, out);
}

// Round 3
// 71.918 us; speedup vs baseline: 1.0599x; 1.0599x over previous
//
#include <hip/hip_runtime.h>

// FinalLayer: out[b,m] = bias + sum_c w_c * sum_n y[b,n,c] * exp(-0.5*(x_n-t_m)^2 * exp(-2*sigma_c))
// Shapes: x(B,N_IN) y(B,N_IN,C) t(B,N_OUT) sigma(C) w(C) b(1); out flat B*N_OUT fp32.
//
// sigma is channel-uniform for these inputs -> exact factorization:
//   out[b,m] = bias + sum_n ytil[b,n] * exp2(-((x_n - t_m)*s)^2),
//   ytil[b,n] = sum_c w_c y[b,n,c],  s = sqrt(0.5*log2(e))*exp(-sigma0)
// Uniformity checked on-device (__ballot); correct per-channel fallback kept.
//
// Round-3 == round-2 resubmit (round-2 bench was a container-acquisition
// failure, kernel never measured). SINGLE dispatch, 64 blocks x 512 threads:
//  - MTILE=64 -> 16 blocks/batch -> prep redundancy 16x (round-1's failed
//    fusion had 64x), ~8 MB L2-resident y traffic total.
//  - 8 waves/block = 2 waves/SIMD on active CUs (round-1 had 1/SIMD: every
//    shuffle/L2 latency fully exposed).
constexpr int Bb   = 4;
constexpr int NIN  = 512;
constexpr int NOUT = 1024;
constexpr int CC   = 64;    // == wavefront size

constexpr int MTILE = 64;   // m per block
constexpr int NW    = 8;    // waves per block

__global__ __launch_bounds__(512) void rbf_fused(
    const float* __restrict__ x,     const float* __restrict__ y,
    const float* __restrict__ t,     const float* __restrict__ sigma,
    const float* __restrict__ w,     const float* __restrict__ bias,
    float* __restrict__ out)
{
    __shared__ float xs[NIN];        // x[b,n] * s
    __shared__ float yt[NIN];        // sum_c w_c y[b,n,c]
    __shared__ float part[NW * 64];  // [g][m-lane] cross-wave partials

    const int tid  = threadIdx.x;
    const int lane = tid & 63;
    const int g    = tid >> 6;                 // wave id 0..7
    const int mt   = blockIdx.x & (NOUT / MTILE - 1);  // m-tile 0..15
    const int b    = blockIdx.x >> 4;          // batch

    const float s0  = sigma[0];
    const bool  uni = (__ballot(sigma[lane] == s0) == ~0ull);  // channel-uniform?

    if (uni) {
        const float s = 0.84932180f * __expf(-s0);  // sqrt(0.5*log2e)*exp(-sigma0)

        // ---- phase 1a: xs[n] = x[b,n]*s (coalesced, 1 per thread) ----
        if (tid < NIN) xs[tid] = x[b * NIN + tid] * s;

        // ---- phase 1b: yt[n] = sum_c w_c y[b,n,c]; wave g owns rows g*64.. ----
        // lane = (row r 0..3) x (float4 group cg 0..15); wave reads 1 KB/iter contiguous
        const int    r  = lane >> 4;
        const int    cg = lane & 15;
        const float4 wv = ((const float4*)w)[cg];
        const float4* __restrict__ y4 = (const float4*)(y + (size_t)b * NIN * CC);
#pragma unroll 4
        for (int it = 0; it < 16; ++it) {
            const int n = g * 64 + it * 4 + r;
            const float4 v = y4[n * (CC / 4) + cg];      // coalesced dwordx4
            float p = v.x * wv.x + v.y * wv.y + v.z * wv.z + v.w * wv.w;
            p += __shfl_xor(p, 1, 64);                   // reduce over cg (16 lanes)
            p += __shfl_xor(p, 2, 64);
            p += __shfl_xor(p, 4, 64);
            p += __shfl_xor(p, 8, 64);
            if (cg == 0) yt[n] = p;
        }
        __syncthreads();

        // ---- phase 2: m = mt*64 + lane; wave g sums its 64-n slice ----
        const int   m  = mt * MTILE + lane;
        const float tm = t[b * NOUT + m] * s;
        const float* __restrict__ xg = xs + g * 64;  // wave-uniform -> LDS broadcast
        const float* __restrict__ yg = yt + g * 64;
        float a0 = 0.f, a1 = 0.f, a2 = 0.f, a3 = 0.f;
#pragma unroll 4
        for (int n = 0; n < 64; n += 4) {   // 4 chains for exp-latency ILP
            const float d0 = xg[n + 0] - tm;
            const float d1 = xg[n + 1] - tm;
            const float d2 = xg[n + 2] - tm;
            const float d3 = xg[n + 3] - tm;
            a0 += __builtin_amdgcn_exp2f(-(d0 * d0)) * yg[n + 0];
            a1 += __builtin_amdgcn_exp2f(-(d1 * d1)) * yg[n + 1];
            a2 += __builtin_amdgcn_exp2f(-(d2 * d2)) * yg[n + 2];
            a3 += __builtin_amdgcn_exp2f(-(d3 * d3)) * yg[n + 3];
        }
        part[g * 64 + lane] = (a0 + a1) + (a2 + a3);
        __syncthreads();
        if (g == 0) {   // stride-1 LDS reads (2 lanes/bank = free), coalesced store
            const float rsum = ((part[lane]       + part[64 + lane]) +
                                (part[128 + lane] + part[192 + lane])) +
                               ((part[256 + lane] + part[320 + lane]) +
                                (part[384 + lane] + part[448 + lane])) + bias[0];
            out[b * NOUT + m] = rsum;
        }
    } else {
        // general per-channel path: lane = c; wave g handles 8 m values
        const float kc2 = -0.72134752f * __expf(-2.0f * sigma[lane]);
        const float wc  = w[lane];
        const float* __restrict__ xb = x + b * NIN;
        const float* __restrict__ yb = y + (size_t)b * NIN * CC + lane;
        for (int j = 0; j < 8; ++j) {
            const int   mm = mt * MTILE + g * 8 + j;
            const float tm = t[b * NOUT + mm];
            float acc = 0.f;
            for (int n = 0; n < NIN; ++n) {
                const float d = xb[n] - tm;
                acc += __builtin_amdgcn_exp2f(d * d * kc2) * yb[(size_t)n * CC];
            }
            float p = acc * wc;
#pragma unroll
            for (int off = 32; off > 0; off >>= 1) p += __shfl_xor(p, off, 64);
            if (lane == 0) out[b * NOUT + mm] = p + bias[0];
        }
    }
}

extern "C" void kernel_launch(void* const* d_in, const int* in_sizes, int n_in,
                              void* d_out, int out_size, void* d_ws, size_t ws_size,
                              hipStream_t stream) {
    const float* x     = (const float*)d_in[0];
    const float* y     = (const float*)d_in[1];
    const float* t     = (const float*)d_in[2];
    const float* sigma = (const float*)d_in[3];
    const float* w     = (const float*)d_in[4];
    const float* bias  = (const float*)d_in[5];
    float* out = (float*)d_out;
    (void)d_ws; (void)ws_size;

    rbf_fused<<<Bb * (NOUT / MTILE), 512, 0, stream>>>(x, y, t, sigma, w, bias, out);
}

// Round 4
// 68.319 us; speedup vs baseline: 1.1158x; 1.0527x over previous
//
#include <hip/hip_runtime.h>

// FinalLayer: out[b,m] = bias + sum_c w_c * sum_n y[b,n,c] * exp(-0.5*(x_n-t_m)^2 * exp(-2*sigma_c))
// Shapes: x(B,N_IN) y(B,N_IN,C) t(B,N_OUT) sigma(C) w(C) b(1); out flat B*N_OUT fp32.
//
// sigma is channel-uniform for these inputs -> exact factorization:
//   out[b,m] = bias + sum_n ytil[b,n] * exp2(-((x_n - t_m)*s)^2),
//   ytil[b,n] = sum_c w_c y[b,n,c],  s^2 = 0.5*log2(e)*exp(-2*sigma0)
// Uniformity checked on-device (__ballot); correct per-channel fallback kept.
//
// Round-4: REVERT to the proven two-dispatch structure (67.0 µs baseline).
// Fusion measured twice: 64x-redundant=76.2, 16x-redundant=71.9 -> extrapolated
// 1x ~69-70, all worse than split. Under graph capture the 2nd node is ~free;
// fusion only adds barrier-serialized latency + redundant y re-reduction.
// Single change vs round-0: rbf_prep vectorized (float4 dot, 16B/lane, 4-step
// 16-lane reduce instead of 4B/lane + 6-step butterfly). rbf_main untouched.
constexpr int Bb   = 4;
constexpr int NIN  = 512;
constexpr int NOUT = 1024;
constexpr int CC   = 64;    // == wavefront size

constexpr int MTILE = 64;          // m per block (main)
constexpr int NGRP  = 4;           // internal n-split (one wave per group)
constexpr int NPER  = NIN / NGRP;  // 128

// ---- prep: ytil[row] = sum_c w[c]*y[row,c], row = b*NIN+n (0..2047) -------
// 128 blocks x 4 waves; wave handles 4 rows: lane = (row r 0..3) x (f4 grp cg)
__global__ __launch_bounds__(256) void rbf_prep(
    const float* __restrict__ y, const float* __restrict__ w,
    float* __restrict__ ytil)
{
    const int lane = threadIdx.x & 63;
    const int g    = threadIdx.x >> 6;           // wave 0..3
    const int r    = lane >> 4;                  // row within 4-row group
    const int cg   = lane & 15;                  // float4 group 0..15
    const int row  = blockIdx.x * 16 + g * 4 + r;

    const float4 wv = ((const float4*)w)[cg];
    const float4 v  = ((const float4*)y)[(size_t)row * (CC / 4) + cg];  // 1KB/wave
    float p = v.x * wv.x + v.y * wv.y + v.z * wv.z + v.w * wv.w;
    p += __shfl_xor(p, 1, 64);                   // reduce over cg (16 lanes)
    p += __shfl_xor(p, 2, 64);
    p += __shfl_xor(p, 4, 64);
    p += __shfl_xor(p, 8, 64);
    if (cg == 0) ytil[row] = p;                  // 4 consecutive dwords/wave
}

// ---- main: 64 blocks = B x 16 m-tiles; block = 64 m x 4 n-groups ---------
__global__ __launch_bounds__(256) void rbf_main(
    const float* __restrict__ x,     const float* __restrict__ y,
    const float* __restrict__ t,     const float* __restrict__ sigma,
    const float* __restrict__ w,     const float* __restrict__ bias,
    const float* __restrict__ ytil,  float* __restrict__ out)
{
    __shared__ float part[NGRP * MTILE];
    const int tid  = threadIdx.x;
    const int lane = tid & 63;
    const int g    = tid >> 6;               // n-group == wave id
    const int mt   = blockIdx.x & 15;        // m-tile within batch
    const int b    = blockIdx.x >> 4;        // batch
    const int m    = mt * MTILE + lane;

    const float s0  = sigma[0];
    const bool  uni = (__ballot(sigma[lane] == s0) == ~0ull);  // wave-uniform

    if (uni) {
        // s = sqrt(0.5*log2(e))*exp(-sigma0); arg = -((x-t)*s)^2 in log2 domain
        const float s  = 0.84932180f * __expf(-s0);
        const float tm = t[b * NOUT + m] * s;
        const float* __restrict__ xb = x    + b * NIN + g * NPER;  // uniform -> s_load
        const float* __restrict__ yb = ytil + b * NIN + g * NPER;  // uniform -> s_load
        float a0 = 0.f, a1 = 0.f, a2 = 0.f, a3 = 0.f;
#pragma unroll 8
        for (int n = 0; n < NPER; n += 4) {  // 4 accumulators for exp-latency ILP
            const float d0 = xb[n + 0] * s - tm;
            const float d1 = xb[n + 1] * s - tm;
            const float d2 = xb[n + 2] * s - tm;
            const float d3 = xb[n + 3] * s - tm;
            a0 += __builtin_amdgcn_exp2f(-(d0 * d0)) * yb[n + 0];
            a1 += __builtin_amdgcn_exp2f(-(d1 * d1)) * yb[n + 1];
            a2 += __builtin_amdgcn_exp2f(-(d2 * d2)) * yb[n + 2];
            a3 += __builtin_amdgcn_exp2f(-(d3 * d3)) * yb[n + 3];
        }
        part[tid] = (a0 + a1) + (a2 + a3);
        __syncthreads();
        if (g == 0) {
            const float r = (part[lane] + part[64 + lane]) +
                            (part[128 + lane] + part[192 + lane]) + bias[0];
            out[b * NOUT + m] = r;  // coalesced 256B store, no atomics
        }
    } else {
        // general per-channel path: lane = c; wave g handles 16 m values
        const float kc2 = -0.72134752f * __expf(-2.0f * sigma[lane]);
        const float wc  = w[lane];
        const float* __restrict__ xb = x + b * NIN;
        const float* __restrict__ yb = y + (size_t)b * NIN * CC + lane;
        for (int j = 0; j < 16; ++j) {
            const int   mm = mt * MTILE + g * 16 + j;
            const float tm = t[b * NOUT + mm];
            float acc = 0.f;
            for (int n = 0; n < NIN; ++n) {
                const float d = xb[n] - tm;
                acc += __builtin_amdgcn_exp2f(d * d * kc2) * yb[(size_t)n * CC];
            }
            float p = acc * wc;
#pragma unroll
            for (int off = 32; off > 0; off >>= 1) p += __shfl_xor(p, off, 64);
            if (lane == 0) out[b * NOUT + mm] = p + bias[0];
        }
    }
}

extern "C" void kernel_launch(void* const* d_in, const int* in_sizes, int n_in,
                              void* d_out, int out_size, void* d_ws, size_t ws_size,
                              hipStream_t stream) {
    const float* x     = (const float*)d_in[0];
    const float* y     = (const float*)d_in[1];
    const float* t     = (const float*)d_in[2];
    const float* sigma = (const float*)d_in[3];
    const float* w     = (const float*)d_in[4];
    const float* bias  = (const float*)d_in[5];
    float* out  = (float*)d_out;
    float* ytil = (float*)d_ws;  // 2048 floats = 8 KB scratch

    rbf_prep<<<Bb * NIN / 16, 256, 0, stream>>>(y, w, ytil);
    rbf_main<<<Bb * (NOUT / MTILE), 256, 0, stream>>>(x, y, t, sigma, w, bias, ytil, out);
}